// Round 1
// baseline (577.424 us; speedup 1.0000x reference)
//
#include <hip/hip_runtime.h>
#include <hip/hip_bf16.h>
#include <math.h>

// ---------------------------------------------------------------------------
// GCN 2-layer: x[100000,128] @ W1[128,64] -> sym-norm aggregate -> relu
//              -> @ W2[64,40] -> aggregate -> + b2 -> log_softmax
// edge_index int32 [2,E]; self-loops added (fused into epilogue kernels).
// ---------------------------------------------------------------------------

#define WAVE 64

// deg[i] = (number of edges with dst==i); self-loop +1 added in rsqrt kernel
__global__ void deg_kernel(const int* __restrict__ dst, float* __restrict__ deg, int E) {
    int i = blockIdx.x * blockDim.x + threadIdx.x;
    if (i < E) atomicAdd(&deg[dst[i]], 1.0f);
}

__global__ void rsqrt_kernel(float* __restrict__ d, int n) {
    int i = blockIdx.x * blockDim.x + threadIdx.x;
    if (i < n) d[i] = rsqrtf(d[i] + 1.0f);   // +1 = self-loop; deg>=1 always
}

// H[n,C] = X[n,K] @ W[K,C], W staged in LDS, thread per output element.
template <int K, int C>
__global__ void gemm_kernel(const float* __restrict__ X, const float* __restrict__ W,
                            float* __restrict__ H, int n) {
    __shared__ float Ws[K * C];
    for (int i = threadIdx.x; i < K * C; i += blockDim.x) Ws[i] = W[i];
    __syncthreads();
    int total = n * C;
    for (int idx = blockIdx.x * blockDim.x + threadIdx.x; idx < total;
         idx += gridDim.x * blockDim.x) {
        int row = idx / C;
        int c   = idx - row * C;
        const float4* x4 = reinterpret_cast<const float4*>(X + (size_t)row * K);
        float acc = 0.0f;
#pragma unroll
        for (int k = 0; k < K / 4; ++k) {
            float4 v = x4[k];
            acc += v.x * Ws[(4 * k + 0) * C + c];
            acc += v.y * Ws[(4 * k + 1) * C + c];
            acc += v.z * Ws[(4 * k + 2) * C + c];
            acc += v.w * Ws[(4 * k + 3) * C + c];
        }
        H[idx] = acc;
    }
}

// Layer-1 scatter: one wave per edge, 64 features per edge (fully coalesced).
__global__ void scatter64_kernel(const float* __restrict__ H, const int* __restrict__ src,
                                 const int* __restrict__ dst, const float* __restrict__ dinv,
                                 float* __restrict__ AGG, int E) {
    int wave = (blockIdx.x * blockDim.x + threadIdx.x) >> 6;
    int lane = threadIdx.x & 63;
    if (wave >= E) return;
    int s = src[wave];
    int t = dst[wave];
    float nrm = dinv[s] * dinv[t];
    atomicAdd(&AGG[(size_t)t * 64 + lane], H[(size_t)s * 64 + lane] * nrm);
}

// out1 = relu(agg1 + h1*dinv^2 + b1)   (self-loop message fused here)
__global__ void relu_bias_kernel(float* __restrict__ AGG, const float* __restrict__ H,
                                 const float* __restrict__ dinv, const float* __restrict__ b,
                                 int n) {
    int total = n * 64;
    int idx = blockIdx.x * blockDim.x + threadIdx.x;
    if (idx >= total) return;
    int row = idx >> 6;
    int d   = idx & 63;
    float di = dinv[row];
    float v = AGG[idx] + H[idx] * di * di + b[d];
    AGG[idx] = v > 0.0f ? v : 0.0f;
}

// Layer-2 scatter: thread per (edge, feature), 40 features.
__global__ void scatter40_kernel(const float* __restrict__ H, const int* __restrict__ src,
                                 const int* __restrict__ dst, const float* __restrict__ dinv,
                                 float* __restrict__ AGG, int E) {
    int idx = blockIdx.x * blockDim.x + threadIdx.x;
    int total = E * 40;
    if (idx >= total) return;
    int e = idx / 40;
    int d = idx - e * 40;
    int s = src[e];
    int t = dst[e];
    float nrm = dinv[s] * dinv[t];
    atomicAdd(&AGG[(size_t)t * 40 + d], H[(size_t)s * 40 + d] * nrm);
}

// out = log_softmax(agg2 + h2*dinv^2 + b2), one wave per row (40 active lanes)
__global__ void finish_kernel(const float* __restrict__ AGG, const float* __restrict__ H,
                              const float* __restrict__ dinv, const float* __restrict__ b,
                              float* __restrict__ out, int n) {
    int wave = (blockIdx.x * blockDim.x + threadIdx.x) >> 6;
    int lane = threadIdx.x & 63;
    if (wave >= n) return;
    float di = dinv[wave];
    float self2 = di * di;
    float v = -INFINITY;
    if (lane < 40) v = AGG[(size_t)wave * 40 + lane] + H[(size_t)wave * 40 + lane] * self2 + b[lane];
    float m = v;
#pragma unroll
    for (int off = 32; off > 0; off >>= 1) m = fmaxf(m, __shfl_xor(m, off));
    float ex = (lane < 40) ? expf(v - m) : 0.0f;
    float ssum = ex;
#pragma unroll
    for (int off = 32; off > 0; off >>= 1) ssum += __shfl_xor(ssum, off);
    if (lane < 40) out[(size_t)wave * 40 + lane] = v - m - logf(ssum);
}

extern "C" void kernel_launch(void* const* d_in, const int* in_sizes, int n_in,
                              void* d_out, int out_size, void* d_ws, size_t ws_size,
                              hipStream_t stream) {
    const float* x  = (const float*)d_in[0];
    const int*   ei = (const int*)d_in[1];
    const float* W1 = (const float*)d_in[2];
    const float* b1 = (const float*)d_in[3];
    const float* W2 = (const float*)d_in[4];
    const float* b2 = (const float*)d_in[5];
    float* out = (float*)d_out;

    const int n = in_sizes[0] / 128;   // 100000
    const int E = in_sizes[1] / 2;     // 800000
    const int* src = ei;
    const int* dst = ei + E;

    // workspace layout (floats)
    float* ws = (float*)d_ws;
    float* dinv = ws;                           // n
    float* bufA = ws + 102400;                  // h1 (n*64), later h2 (n*40)
    float* bufB = bufA + (size_t)n * 64;        // agg1 -> out1 (n*64)
    float* bufC = bufB + (size_t)n * 64;        // agg2 (n*40)

    // zero accumulators (harness does not re-poison between replays)
    hipMemsetAsync(dinv, 0, (size_t)n * 4, stream);
    hipMemsetAsync(bufB, 0, (size_t)n * 64 * 4, stream);
    hipMemsetAsync(bufC, 0, (size_t)n * 40 * 4, stream);

    // degree + rsqrt
    deg_kernel<<<(E + 255) / 256, 256, 0, stream>>>(dst, dinv, E);
    rsqrt_kernel<<<(n + 255) / 256, 256, 0, stream>>>(dinv, n);

    // h1 = x @ W1
    gemm_kernel<128, 64><<<4096, 256, 0, stream>>>(x, W1, bufA, n);

    // aggregate layer 1 (edges only; self-loop fused into relu_bias)
    scatter64_kernel<<<(E * WAVE + 255) / 256, 256, 0, stream>>>(bufA, src, dst, dinv, bufB, E);

    // out1 = relu(agg1 + h1*dinv^2 + b1)   (in place in bufB)
    relu_bias_kernel<<<(n * 64 + 255) / 256, 256, 0, stream>>>(bufB, bufA, dinv, b1, n);

    // h2 = out1 @ W2   (reuse bufA)
    gemm_kernel<64, 40><<<4096, 256, 0, stream>>>(bufB, W2, bufA, n);

    // aggregate layer 2
    scatter40_kernel<<<(E * 40 + 255) / 256, 256, 0, stream>>>(bufA, src, dst, dinv, bufC, E);

    // out = log_softmax(agg2 + h2*dinv^2 + b2)
    finish_kernel<<<((size_t)n * WAVE + 255) / 256, 256, 0, stream>>>(bufC, bufA, dinv, b2, out, n);
}

// Round 2
// 256.494 us; speedup vs baseline: 2.2512x; 2.2512x over previous
//
#include <hip/hip_runtime.h>
#include <hip/hip_bf16.h>
#include <math.h>

// ---------------------------------------------------------------------------
// GCN 2-layer, CSR-gather formulation (no float atomics):
//   degi = histogram(dst); dinv = rsqrt(degi+1)
//   counter = exclusive_scan(degi); csr[slot] = (src, dinv[s]*dinv[t])
//   h1 = x @ W1 (register-tiled);  out1 = relu(gather(h1) + self + b1)
//   h2 = out1 @ W2;                out  = log_softmax(gather(h2) + self + b2)
// ---------------------------------------------------------------------------

__global__ void deg_int_kernel(const int* __restrict__ dst, int* __restrict__ degi, int E) {
    int i = blockIdx.x * blockDim.x + threadIdx.x;
    if (i < E) atomicAdd(&degi[dst[i]], 1);
}

// dinv written in place over degi (reinterpret int->float)
__global__ void dinv_kernel(int* __restrict__ degi, int n) {
    int i = blockIdx.x * blockDim.x + threadIdx.x;
    if (i < n) {
        float v = (float)degi[i] + 1.0f;  // +1 self-loop
        ((float*)degi)[i] = rsqrtf(v);
    }
}

// ---- two-level exclusive scan of degi -> counter (1024 items / block) ----
__global__ __launch_bounds__(256) void blocksum_kernel(const int* __restrict__ degi,
                                                       int* __restrict__ partial, int n) {
    __shared__ int sm[256];
    int t = threadIdx.x;
    int base = blockIdx.x * 1024 + t * 4;
    int s = 0;
#pragma unroll
    for (int j = 0; j < 4; ++j) { int i = base + j; if (i < n) s += degi[i]; }
    sm[t] = s;
    __syncthreads();
    for (int off = 128; off > 0; off >>= 1) {
        if (t < off) sm[t] += sm[t + off];
        __syncthreads();
    }
    if (t == 0) partial[blockIdx.x] = sm[0];
}

__global__ __launch_bounds__(256) void scanp_kernel(int* __restrict__ partial, int nb) {
    __shared__ int sm[256];
    int t = threadIdx.x;
    int v = (t < nb) ? partial[t] : 0;
    sm[t] = v;
    __syncthreads();
    for (int off = 1; off < 256; off <<= 1) {
        int x = (t >= off) ? sm[t - off] : 0;
        __syncthreads();
        sm[t] += x;
        __syncthreads();
    }
    if (t < nb) partial[t] = sm[t] - v;  // exclusive
}

__global__ __launch_bounds__(256) void offsets_kernel(const int* __restrict__ degi,
                                                      const int* __restrict__ partial,
                                                      int* __restrict__ counter, int n) {
    __shared__ int sm[256];
    int t = threadIdx.x;
    int base = blockIdx.x * 1024 + t * 4;
    int v[4]; int s = 0;
#pragma unroll
    for (int j = 0; j < 4; ++j) { v[j] = (base + j < n) ? degi[base + j] : 0; s += v[j]; }
    sm[t] = s;
    __syncthreads();
    for (int off = 1; off < 256; off <<= 1) {
        int x = (t >= off) ? sm[t - off] : 0;
        __syncthreads();
        sm[t] += x;
        __syncthreads();
    }
    int run = partial[blockIdx.x] + (sm[t] - s);  // block base + thread-exclusive
#pragma unroll
    for (int j = 0; j < 4; ++j) {
        if (base + j < n) { counter[base + j] = run; run += v[j]; }
    }
}

// fill CSR slots: counter[t] walks from row_start to row_end
__global__ void fill_kernel(const int* __restrict__ src, const int* __restrict__ dst,
                            const float* __restrict__ dinv, int* __restrict__ counter,
                            int2* __restrict__ csr, int E) {
    int e = blockIdx.x * blockDim.x + threadIdx.x;
    if (e >= E) return;
    int s = src[e], t = dst[e];
    float nrm = dinv[s] * dinv[t];
    int pos = atomicAdd(&counter[t], 1);
    csr[pos] = make_int2(s, __float_as_int(nrm));
}

// ---- register-tiled GEMM: H[n,C] = X[n,K] @ W[K,C], 4x4 per thread ----
template <int K, int C, int BM>
__global__ __launch_bounds__(256) void gemm_tiled(const float* __restrict__ X,
                                                  const float* __restrict__ W,
                                                  float* __restrict__ H, int n) {
    constexpr int BK = 32;
    constexpr int XP = 36;               // padded stride (2-way bank max)
    constexpr int ROWG = BM / 4;
    constexpr int COLG = C / 4;
    __shared__ float Xs[BM][XP];
    __shared__ float Ws[BK][C];
    int t = threadIdx.x;
    int tx = t % COLG;                   // col group (4 cols)
    int ty = t / COLG;                   // row group (4 rows)
    bool active = ty < ROWG;
    int rowbase = blockIdx.x * BM;
    float acc[4][4] = {};

    for (int kc = 0; kc < K; kc += BK) {
        // stage X tile (BM x 32), coalesced float4
        for (int fi = t; fi < BM * 8; fi += 256) {
            int row = fi >> 3, kq = fi & 7;
            int gr = rowbase + row; if (gr >= n) gr = n - 1;
            float4 v = *reinterpret_cast<const float4*>(X + (size_t)gr * K + kc + kq * 4);
            *reinterpret_cast<float4*>(&Xs[row][kq * 4]) = v;
        }
        // stage W tile (32 x C), contiguous
        for (int fi = t; fi < BK * C / 4; fi += 256) {
            reinterpret_cast<float4*>(&Ws[0][0])[fi] =
                reinterpret_cast<const float4*>(W + (size_t)kc * C)[fi];
        }
        __syncthreads();
        if (active) {
#pragma unroll
            for (int k0 = 0; k0 < BK; k0 += 4) {
                float4 xq[4], wq[4];
#pragma unroll
                for (int i = 0; i < 4; ++i)
                    xq[i] = *reinterpret_cast<const float4*>(&Xs[ty * 4 + i][k0]);
#pragma unroll
                for (int j = 0; j < 4; ++j)
                    wq[j] = *reinterpret_cast<const float4*>(&Ws[k0 + j][tx * 4]);
#pragma unroll
                for (int i = 0; i < 4; ++i) {
                    const float* xa = reinterpret_cast<const float*>(&xq[i]);
#pragma unroll
                    for (int j = 0; j < 4; ++j) {
                        const float* wb = reinterpret_cast<const float*>(&wq[j]);
                        acc[i][0] += xa[j] * wb[0];
                        acc[i][1] += xa[j] * wb[1];
                        acc[i][2] += xa[j] * wb[2];
                        acc[i][3] += xa[j] * wb[3];
                    }
                }
            }
        }
        __syncthreads();
    }
    if (active) {
#pragma unroll
        for (int i = 0; i < 4; ++i) {
            int gr = rowbase + ty * 4 + i;
            if (gr < n) {
                float4 o = make_float4(acc[i][0], acc[i][1], acc[i][2], acc[i][3]);
                *reinterpret_cast<float4*>(H + (size_t)gr * C + tx * 4) = o;
            }
        }
    }
}

// ---- layer-1 gather: wave per node, lane = feature (64). relu+bias+self fused
__global__ __launch_bounds__(256) void gather64_kernel(const float* __restrict__ H,
                                                       const int2* __restrict__ csr,
                                                       const int* __restrict__ counter,
                                                       const float* __restrict__ dinv,
                                                       const float* __restrict__ b,
                                                       float* __restrict__ out, int n) {
    int node = (blockIdx.x * blockDim.x + threadIdx.x) >> 6;
    int lane = threadIdx.x & 63;
    if (node >= n) return;
    int rs = node ? counter[node - 1] : 0;
    int re = counter[node];
    float di = dinv[node];
    float acc = H[(size_t)node * 64 + lane] * di * di + b[lane];
    int e = rs;
    for (; e + 2 <= re; e += 2) {
        int2 c0 = csr[e], c1 = csr[e + 1];
        acc += H[(size_t)c0.x * 64 + lane] * __int_as_float(c0.y);
        acc += H[(size_t)c1.x * 64 + lane] * __int_as_float(c1.y);
    }
    if (e < re) {
        int2 c0 = csr[e];
        acc += H[(size_t)c0.x * 64 + lane] * __int_as_float(c0.y);
    }
    out[(size_t)node * 64 + lane] = fmaxf(acc, 0.0f);
}

// ---- layer-2 gather + bias + log_softmax: wave per node, lanes 0..39 live
__global__ __launch_bounds__(256) void gather40_kernel(const float* __restrict__ H,
                                                       const int2* __restrict__ csr,
                                                       const int* __restrict__ counter,
                                                       const float* __restrict__ dinv,
                                                       const float* __restrict__ b,
                                                       float* __restrict__ out, int n) {
    int node = (blockIdx.x * blockDim.x + threadIdx.x) >> 6;
    int lane = threadIdx.x & 63;
    if (node >= n) return;
    int f = lane < 40 ? lane : 39;  // clamp; lanes >=40 masked at the end
    int rs = node ? counter[node - 1] : 0;
    int re = counter[node];
    float di = dinv[node];
    float acc = H[(size_t)node * 40 + f] * di * di + b[f];
    int e = rs;
    for (; e + 2 <= re; e += 2) {
        int2 c0 = csr[e], c1 = csr[e + 1];
        acc += H[(size_t)c0.x * 40 + f] * __int_as_float(c0.y);
        acc += H[(size_t)c1.x * 40 + f] * __int_as_float(c1.y);
    }
    if (e < re) {
        int2 c0 = csr[e];
        acc += H[(size_t)c0.x * 40 + f] * __int_as_float(c0.y);
    }
    float v = (lane < 40) ? acc : -INFINITY;
    float m = v;
#pragma unroll
    for (int off = 32; off > 0; off >>= 1) m = fmaxf(m, __shfl_xor(m, off));
    float ex = (lane < 40) ? expf(v - m) : 0.0f;
    float ssum = ex;
#pragma unroll
    for (int off = 32; off > 0; off >>= 1) ssum += __shfl_xor(ssum, off);
    if (lane < 40) out[(size_t)node * 40 + lane] = v - m - logf(ssum);
}

extern "C" void kernel_launch(void* const* d_in, const int* in_sizes, int n_in,
                              void* d_out, int out_size, void* d_ws, size_t ws_size,
                              hipStream_t stream) {
    const float* x  = (const float*)d_in[0];
    const int*   ei = (const int*)d_in[1];
    const float* W1 = (const float*)d_in[2];
    const float* b1 = (const float*)d_in[3];
    const float* W2 = (const float*)d_in[4];
    const float* b2 = (const float*)d_in[5];
    float* out = (float*)d_out;

    const int n = in_sizes[0] / 128;   // 100000
    const int E = in_sizes[1] / 2;     // 800000
    const int* src = ei;
    const int* dst = ei + E;

    auto al = [](size_t x) { return (x + 255) & ~(size_t)255; };
    float* ws = (float*)d_ws;
    size_t o_deg  = 0;                       // n ints -> becomes dinv floats in place
    size_t o_cnt  = al(n);                   // n ints (scan / running counters)
    size_t o_part = o_cnt + al(n);           // block partials (<=256 ints)
    size_t o_csr  = o_part + 1024;           // E int2
    size_t o_h1   = o_csr + al((size_t)2 * E);
    size_t o_out1 = o_h1 + al((size_t)n * 64);
    // h2 aliases h1 (h1 dead after gather64)

    int*   degi    = (int*)(ws + o_deg);
    float* dinv    = (float*)(ws + o_deg);
    int*   counter = (int*)(ws + o_cnt);
    int*   partial = (int*)(ws + o_part);
    int2*  csr     = (int2*)(ws + o_csr);
    float* h1      = ws + o_h1;
    float* out1    = ws + o_out1;
    float* h2      = ws + o_h1;

    const int NB = (n + 1023) / 1024;        // <= 256 for n <= 262144

    hipMemsetAsync(degi, 0, (size_t)n * 4, stream);
    deg_int_kernel<<<(E + 255) / 256, 256, 0, stream>>>(dst, degi, E);
    blocksum_kernel<<<NB, 256, 0, stream>>>(degi, partial, n);
    scanp_kernel<<<1, 256, 0, stream>>>(partial, NB);
    offsets_kernel<<<NB, 256, 0, stream>>>(degi, partial, counter, n);
    dinv_kernel<<<(n + 255) / 256, 256, 0, stream>>>(degi, n);
    fill_kernel<<<(E + 255) / 256, 256, 0, stream>>>(src, dst, dinv, counter, csr, E);

    gemm_tiled<128, 64, 64><<<(n + 63) / 64, 256, 0, stream>>>(x, W1, h1, n);
    gather64_kernel<<<(n + 3) / 4, 256, 0, stream>>>(h1, csr, counter, dinv, b1, out1, n);
    gemm_tiled<64, 40, 96><<<(n + 95) / 96, 256, 0, stream>>>(out1, W2, h2, n);
    gather40_kernel<<<(n + 3) / 4, 256, 0, stream>>>(h2, csr, counter, dinv, b2, out, n);
}

// Round 3
// 231.508 us; speedup vs baseline: 2.4942x; 1.1079x over previous
//
#include <hip/hip_runtime.h>
#include <hip/hip_bf16.h>
#include <math.h>

// ---------------------------------------------------------------------------
// GCN 2-layer, CSR-gather formulation (no float atomics):
//   degi = histogram(dst); dinv = rsqrt(degi+1); counter = exscan(degi)
//   csr[slot] = (src, dinv[s]*dinv[t])
//   h1 = x @ W1;  out1 = relu(gather(h1) + self + b1)
//   agg2 = gather(out1) + self          (linearity: aggregate BEFORE gemm2)
//   out = log_softmax(agg2 @ W2 + b2)   (softmax fused into gemm2 epilogue)
// ---------------------------------------------------------------------------

__global__ void deg_int_kernel(const int* __restrict__ dst, int* __restrict__ degi, int E) {
    int i = blockIdx.x * blockDim.x + threadIdx.x;
    if (i < E) atomicAdd(&degi[dst[i]], 1);
}

__global__ void dinv_kernel(int* __restrict__ degi, int n) {
    int i = blockIdx.x * blockDim.x + threadIdx.x;
    if (i < n) {
        float v = (float)degi[i] + 1.0f;  // +1 self-loop
        ((float*)degi)[i] = rsqrtf(v);
    }
}

// ---- two-level exclusive scan of degi -> counter (1024 items / block) ----
__global__ __launch_bounds__(256) void blocksum_kernel(const int* __restrict__ degi,
                                                       int* __restrict__ partial, int n) {
    __shared__ int sm[256];
    int t = threadIdx.x;
    int base = blockIdx.x * 1024 + t * 4;
    int s = 0;
#pragma unroll
    for (int j = 0; j < 4; ++j) { int i = base + j; if (i < n) s += degi[i]; }
    sm[t] = s;
    __syncthreads();
    for (int off = 128; off > 0; off >>= 1) {
        if (t < off) sm[t] += sm[t + off];
        __syncthreads();
    }
    if (t == 0) partial[blockIdx.x] = sm[0];
}

__global__ __launch_bounds__(256) void scanp_kernel(int* __restrict__ partial, int nb) {
    __shared__ int sm[256];
    int t = threadIdx.x;
    int v = (t < nb) ? partial[t] : 0;
    sm[t] = v;
    __syncthreads();
    for (int off = 1; off < 256; off <<= 1) {
        int x = (t >= off) ? sm[t - off] : 0;
        __syncthreads();
        sm[t] += x;
        __syncthreads();
    }
    if (t < nb) partial[t] = sm[t] - v;  // exclusive
}

__global__ __launch_bounds__(256) void offsets_kernel(const int* __restrict__ degi,
                                                      const int* __restrict__ partial,
                                                      int* __restrict__ counter, int n) {
    __shared__ int sm[256];
    int t = threadIdx.x;
    int base = blockIdx.x * 1024 + t * 4;
    int v[4]; int s = 0;
#pragma unroll
    for (int j = 0; j < 4; ++j) { v[j] = (base + j < n) ? degi[base + j] : 0; s += v[j]; }
    sm[t] = s;
    __syncthreads();
    for (int off = 1; off < 256; off <<= 1) {
        int x = (t >= off) ? sm[t - off] : 0;
        __syncthreads();
        sm[t] += x;
        __syncthreads();
    }
    int run = partial[blockIdx.x] + (sm[t] - s);
#pragma unroll
    for (int j = 0; j < 4; ++j) {
        if (base + j < n) { counter[base + j] = run; run += v[j]; }
    }
}

// fill CSR slots; after this, counter[i] == row_end(i) == row_start(i+1)
__global__ void fill_kernel(const int* __restrict__ src, const int* __restrict__ dst,
                            const float* __restrict__ dinv, int* __restrict__ counter,
                            int2* __restrict__ csr, int E) {
    int e = blockIdx.x * blockDim.x + threadIdx.x;
    if (e >= E) return;
    int s = src[e], t = dst[e];
    float nrm = dinv[s] * dinv[t];
    int pos = atomicAdd(&counter[t], 1);
    csr[pos] = make_int2(s, __float_as_int(nrm));
}

// ---- register-tiled GEMM1: H[n,64] = X[n,128] @ W[128,64] ----
template <int K, int C, int BM>
__global__ __launch_bounds__(256) void gemm_tiled(const float* __restrict__ X,
                                                  const float* __restrict__ W,
                                                  float* __restrict__ H, int n) {
    constexpr int BK = 32;
    constexpr int XP = 36;
    constexpr int ROWG = BM / 4;
    constexpr int COLG = C / 4;
    __shared__ float Xs[BM][XP];
    __shared__ float Ws[BK][C];
    int t = threadIdx.x;
    int tx = t % COLG;
    int ty = t / COLG;
    bool active = ty < ROWG;
    int rowbase = blockIdx.x * BM;
    float acc[4][4] = {};

    for (int kc = 0; kc < K; kc += BK) {
        for (int fi = t; fi < BM * 8; fi += 256) {
            int row = fi >> 3, kq = fi & 7;
            int gr = rowbase + row; if (gr >= n) gr = n - 1;
            float4 v = *reinterpret_cast<const float4*>(X + (size_t)gr * K + kc + kq * 4);
            *reinterpret_cast<float4*>(&Xs[row][kq * 4]) = v;
        }
        for (int fi = t; fi < BK * C / 4; fi += 256) {
            reinterpret_cast<float4*>(&Ws[0][0])[fi] =
                reinterpret_cast<const float4*>(W + (size_t)kc * C)[fi];
        }
        __syncthreads();
        if (active) {
#pragma unroll
            for (int k0 = 0; k0 < BK; k0 += 4) {
                float4 xq[4], wq[4];
#pragma unroll
                for (int i = 0; i < 4; ++i)
                    xq[i] = *reinterpret_cast<const float4*>(&Xs[ty * 4 + i][k0]);
#pragma unroll
                for (int j = 0; j < 4; ++j)
                    wq[j] = *reinterpret_cast<const float4*>(&Ws[k0 + j][tx * 4]);
#pragma unroll
                for (int i = 0; i < 4; ++i) {
                    const float* xa = reinterpret_cast<const float*>(&xq[i]);
#pragma unroll
                    for (int j = 0; j < 4; ++j) {
                        const float* wb = reinterpret_cast<const float*>(&wq[j]);
                        acc[i][0] += xa[j] * wb[0];
                        acc[i][1] += xa[j] * wb[1];
                        acc[i][2] += xa[j] * wb[2];
                        acc[i][3] += xa[j] * wb[3];
                    }
                }
            }
        }
        __syncthreads();
    }
    if (active) {
#pragma unroll
        for (int i = 0; i < 4; ++i) {
            int gr = rowbase + ty * 4 + i;
            if (gr < n) {
                float4 o = make_float4(acc[i][0], acc[i][1], acc[i][2], acc[i][3]);
                *reinterpret_cast<float4*>(H + (size_t)gr * C + tx * 4) = o;
            }
        }
    }
}

// ---- gather over 64-feature rows: wave per node, 16 lanes x float4 per edge,
//      4 edges in flight; butterfly (xor 16,32) combines the 4 groups.
template <bool RELU, bool BIAS>
__global__ __launch_bounds__(256) void gather64v_kernel(const float4* __restrict__ H4,
                                                        const int2* __restrict__ csr,
                                                        const int* __restrict__ counter,
                                                        const float* __restrict__ dinv,
                                                        const float* __restrict__ b,
                                                        float4* __restrict__ out4, int n) {
    int node = (blockIdx.x * blockDim.x + threadIdx.x) >> 6;
    if (node >= n) return;
    int lane = threadIdx.x & 63;
    int g = lane >> 4, fl = lane & 15;
    int rs = node ? counter[node - 1] : 0;
    int re = counter[node];
    float4 acc = make_float4(0.f, 0.f, 0.f, 0.f);
    for (int e = rs + g; e < re; e += 4) {
        int2 c = csr[e];
        float nrm = __int_as_float(c.y);
        float4 v = H4[(size_t)c.x * 16 + fl];
        acc.x += v.x * nrm; acc.y += v.y * nrm;
        acc.z += v.z * nrm; acc.w += v.w * nrm;
    }
    if (g == 0) {  // self-loop + bias counted exactly once (pre-butterfly)
        float di = dinv[node];
        float d2 = di * di;
        float4 v = H4[(size_t)node * 16 + fl];
        acc.x += v.x * d2; acc.y += v.y * d2;
        acc.z += v.z * d2; acc.w += v.w * d2;
        if (BIAS) {
            float4 bb = reinterpret_cast<const float4*>(b)[fl];
            acc.x += bb.x; acc.y += bb.y; acc.z += bb.z; acc.w += bb.w;
        }
    }
#pragma unroll
    for (int off = 16; off <= 32; off <<= 1) {
        acc.x += __shfl_xor(acc.x, off);
        acc.y += __shfl_xor(acc.y, off);
        acc.z += __shfl_xor(acc.z, off);
        acc.w += __shfl_xor(acc.w, off);
    }
    if (g == 0) {
        if (RELU) {
            acc.x = fmaxf(acc.x, 0.f); acc.y = fmaxf(acc.y, 0.f);
            acc.z = fmaxf(acc.z, 0.f); acc.w = fmaxf(acc.w, 0.f);
        }
        out4[(size_t)node * 16 + fl] = acc;
    }
}

// ---- GEMM2 + bias + log_softmax fused: out = log_softmax(X @ W2 + b2) ----
__global__ __launch_bounds__(256) void gemm2_softmax_kernel(const float* __restrict__ X,
                                                            const float* __restrict__ W,
                                                            const float* __restrict__ b,
                                                            float* __restrict__ out, int n) {
    constexpr int BM = 96, K = 64, C = 40, XP = 68, HP = 41;
    __shared__ float Xs[BM * XP];     // 26112 B; reused as Hs[96][41] after compute
    __shared__ float Ws[K * C];
    __shared__ float bs[C];
    __shared__ float rowm[BM], rowls[BM];
    int t = threadIdx.x;
    int tx = t % (C / 4);             // 0..9
    int ty = t / (C / 4);             // 0..25
    bool active = ty < BM / 4;        // ty < 24
    int rowbase = blockIdx.x * BM;

    for (int i = t; i < K * C / 4; i += 256)
        ((float4*)Ws)[i] = ((const float4*)W)[i];
    if (t < C) bs[t] = b[t];
    for (int fi = t; fi < BM * 16; fi += 256) {
        int row = fi >> 4, kq = fi & 15;
        int gr = rowbase + row; if (gr >= n) gr = n - 1;
        *reinterpret_cast<float4*>(&Xs[row * XP + kq * 4]) =
            reinterpret_cast<const float4*>(X + (size_t)gr * K)[kq];
    }
    __syncthreads();

    float acc[4][4] = {};
    if (active) {
#pragma unroll
        for (int k0 = 0; k0 < K; k0 += 4) {
            float4 xq[4], wq[4];
#pragma unroll
            for (int i = 0; i < 4; ++i)
                xq[i] = *reinterpret_cast<const float4*>(&Xs[(ty * 4 + i) * XP + k0]);
#pragma unroll
            for (int j = 0; j < 4; ++j)
                wq[j] = *reinterpret_cast<const float4*>(&Ws[(k0 + j) * C + tx * 4]);
#pragma unroll
            for (int i = 0; i < 4; ++i) {
                const float* xa = reinterpret_cast<const float*>(&xq[i]);
#pragma unroll
                for (int j = 0; j < 4; ++j) {
                    const float* wb = reinterpret_cast<const float*>(&wq[j]);
                    acc[i][0] += xa[j] * wb[0];
                    acc[i][1] += xa[j] * wb[1];
                    acc[i][2] += xa[j] * wb[2];
                    acc[i][3] += xa[j] * wb[3];
                }
            }
        }
    }
    __syncthreads();                  // everyone done reading Xs
    float* Hs = Xs;                   // reuse as [BM][41]
    if (active) {
#pragma unroll
        for (int i = 0; i < 4; ++i) {
            int r = ty * 4 + i;
#pragma unroll
            for (int j = 0; j < 4; ++j)
                Hs[r * HP + tx * 4 + j] = acc[i][j] + bs[tx * 4 + j];
        }
    }
    __syncthreads();
    if (t < BM) {
        float m = -INFINITY;
        for (int j = 0; j < C; ++j) m = fmaxf(m, Hs[t * HP + j]);
        float s = 0.f;
        for (int j = 0; j < C; ++j) s += __expf(Hs[t * HP + j] - m);
        rowm[t] = m; rowls[t] = __logf(s);
    }
    __syncthreads();
    for (int idx = t; idx < BM * C; idx += 256) {
        int r = idx / C, c = idx - r * C;
        int gr = rowbase + r;
        if (gr < n) out[(size_t)gr * C + c] = Hs[r * HP + c] - rowm[r] - rowls[r];
    }
}

extern "C" void kernel_launch(void* const* d_in, const int* in_sizes, int n_in,
                              void* d_out, int out_size, void* d_ws, size_t ws_size,
                              hipStream_t stream) {
    const float* x  = (const float*)d_in[0];
    const int*   ei = (const int*)d_in[1];
    const float* W1 = (const float*)d_in[2];
    const float* b1 = (const float*)d_in[3];
    const float* W2 = (const float*)d_in[4];
    const float* b2 = (const float*)d_in[5];
    float* out = (float*)d_out;

    const int n = in_sizes[0] / 128;   // 100000
    const int E = in_sizes[1] / 2;     // 800000
    const int* src = ei;
    const int* dst = ei + E;

    auto al = [](size_t x) { return (x + 255) & ~(size_t)255; };
    float* ws = (float*)d_ws;
    size_t o_deg  = 0;                       // n ints -> dinv floats in place
    size_t o_cnt  = al(n);                   // n ints
    size_t o_part = o_cnt + al(n);           // <=256 ints
    size_t o_csr  = o_part + 1024;           // E int2
    size_t o_h1   = o_csr + al((size_t)2 * E);   // n*64 (h1, later agg2)
    size_t o_out1 = o_h1 + al((size_t)n * 64);   // n*64

    int*   degi    = (int*)(ws + o_deg);
    float* dinv    = (float*)(ws + o_deg);
    int*   counter = (int*)(ws + o_cnt);
    int*   partial = (int*)(ws + o_part);
    int2*  csr     = (int2*)(ws + o_csr);
    float* h1      = ws + o_h1;
    float* out1    = ws + o_out1;
    float* agg2    = ws + o_h1;              // h1 dead after gather #1

    const int NB = (n + 1023) / 1024;

    hipMemsetAsync(degi, 0, (size_t)n * 4, stream);
    deg_int_kernel<<<(E + 255) / 256, 256, 0, stream>>>(dst, degi, E);
    blocksum_kernel<<<NB, 256, 0, stream>>>(degi, partial, n);
    scanp_kernel<<<1, 256, 0, stream>>>(partial, NB);
    offsets_kernel<<<NB, 256, 0, stream>>>(degi, partial, counter, n);
    dinv_kernel<<<(n + 255) / 256, 256, 0, stream>>>(degi, n);
    fill_kernel<<<(E + 255) / 256, 256, 0, stream>>>(src, dst, dinv, counter, csr, E);

    gemm_tiled<128, 64, 64><<<(n + 63) / 64, 256, 0, stream>>>(x, W1, h1, n);
    gather64v_kernel<true, true><<<(n + 3) / 4, 256, 0, stream>>>(
        (const float4*)h1, csr, counter, dinv, b1, (float4*)out1, n);
    gather64v_kernel<false, false><<<(n + 3) / 4, 256, 0, stream>>>(
        (const float4*)out1, csr, counter, dinv, nullptr, (float4*)agg2, n);
    gemm2_softmax_kernel<<<(n + 95) / 96, 256, 0, stream>>>(agg2, W2, b2, out, n);
}

// Round 4
// 220.754 us; speedup vs baseline: 2.6157x; 1.0487x over previous
//
#include <hip/hip_runtime.h>
#include <hip/hip_bf16.h>
#include <hip/hip_fp16.h>
#include <math.h>

// ---------------------------------------------------------------------------
// GCN 2-layer, CSR-gather formulation, fp16 intermediate storage:
//   degi = histogram(dst); counter = exscan(degi); dinv = rsqrt(degi+1)
//   csr[slot] = (src, dinv[s]*dinv[t])
//   h1(fp16) = x @ W1;  out1(fp16) = relu(gather(h1) + self + b1)
//   agg2(fp16) = gather(out1) + self     (linearity: aggregate BEFORE gemm2)
//   out = log_softmax(agg2 @ W2 + b2)    (softmax fused into gemm2 epilogue)
// ---------------------------------------------------------------------------

__global__ void deg_int_kernel(const int* __restrict__ dst, int* __restrict__ degi, int E) {
    int i = blockIdx.x * blockDim.x + threadIdx.x;
    if (i < E) atomicAdd(&degi[dst[i]], 1);
}

// ---- two-level exclusive scan of degi -> counter (1024 items / block) ----
__global__ __launch_bounds__(256) void blocksum_kernel(const int* __restrict__ degi,
                                                       int* __restrict__ partial, int n) {
    __shared__ int sm[256];
    int t = threadIdx.x;
    int base = blockIdx.x * 1024 + t * 4;
    int s = 0;
#pragma unroll
    for (int j = 0; j < 4; ++j) { int i = base + j; if (i < n) s += degi[i]; }
    sm[t] = s;
    __syncthreads();
    for (int off = 128; off > 0; off >>= 1) {
        if (t < off) sm[t] += sm[t + off];
        __syncthreads();
    }
    if (t == 0) partial[blockIdx.x] = sm[0];
}

__global__ __launch_bounds__(256) void scanp_kernel(int* __restrict__ partial, int nb) {
    __shared__ int sm[256];
    int t = threadIdx.x;
    int v = (t < nb) ? partial[t] : 0;
    sm[t] = v;
    __syncthreads();
    for (int off = 1; off < 256; off <<= 1) {
        int x = (t >= off) ? sm[t - off] : 0;
        __syncthreads();
        sm[t] += x;
        __syncthreads();
    }
    if (t < nb) partial[t] = sm[t] - v;  // exclusive
}

// counter = exscan(degi); also degi <- rsqrt(degi+1) in place (dinv)
__global__ __launch_bounds__(256) void offsets_kernel(int* __restrict__ degi,
                                                      const int* __restrict__ partial,
                                                      int* __restrict__ counter, int n) {
    __shared__ int sm[256];
    int t = threadIdx.x;
    int base = blockIdx.x * 1024 + t * 4;
    int v[4]; int s = 0;
#pragma unroll
    for (int j = 0; j < 4; ++j) { v[j] = (base + j < n) ? degi[base + j] : 0; s += v[j]; }
    sm[t] = s;
    __syncthreads();
    for (int off = 1; off < 256; off <<= 1) {
        int x = (t >= off) ? sm[t - off] : 0;
        __syncthreads();
        sm[t] += x;
        __syncthreads();
    }
    int run = partial[blockIdx.x] + (sm[t] - s);
#pragma unroll
    for (int j = 0; j < 4; ++j) {
        if (base + j < n) {
            counter[base + j] = run; run += v[j];
            ((float*)degi)[base + j] = rsqrtf((float)v[j] + 1.0f);  // +1 self-loop
        }
    }
}

// fill CSR slots; after this, counter[i] == row_end(i) == row_start(i+1)
__global__ void fill_kernel(const int* __restrict__ src, const int* __restrict__ dst,
                            const float* __restrict__ dinv, int* __restrict__ counter,
                            int2* __restrict__ csr, int E) {
    int e = blockIdx.x * blockDim.x + threadIdx.x;
    if (e >= E) return;
    int s = src[e], t = dst[e];
    float nrm = dinv[s] * dinv[t];
    int pos = atomicAdd(&counter[t], 1);
    csr[pos] = make_int2(s, __float_as_int(nrm));
}

// ---- GEMM1: H[n,64](fp16) = X[n,128] @ W[128,64], 4x4 regs/thread ----
template <int K, int C, int BM>
__global__ __launch_bounds__(256) void gemm_tiled_h(const float* __restrict__ X,
                                                    const float* __restrict__ W,
                                                    __half* __restrict__ H, int n) {
    constexpr int BK = 32;
    constexpr int XP = 36;
    constexpr int ROWG = BM / 4;
    constexpr int COLG = C / 4;
    __shared__ float Xs[BM][XP];
    __shared__ float Ws[BK][C];
    int t = threadIdx.x;
    int tx = t % COLG;
    int ty = t / COLG;
    bool active = ty < ROWG;
    int rowbase = blockIdx.x * BM;
    float acc[4][4] = {};

    for (int kc = 0; kc < K; kc += BK) {
        for (int fi = t; fi < BM * 8; fi += 256) {
            int row = fi >> 3, kq = fi & 7;
            int gr = rowbase + row; if (gr >= n) gr = n - 1;
            float4 v = *reinterpret_cast<const float4*>(X + (size_t)gr * K + kc + kq * 4);
            *reinterpret_cast<float4*>(&Xs[row][kq * 4]) = v;
        }
        for (int fi = t; fi < BK * C / 4; fi += 256) {
            reinterpret_cast<float4*>(&Ws[0][0])[fi] =
                reinterpret_cast<const float4*>(W + (size_t)kc * C)[fi];
        }
        __syncthreads();
        if (active) {
#pragma unroll
            for (int k0 = 0; k0 < BK; k0 += 4) {
                float4 xq[4], wq[4];
#pragma unroll
                for (int i = 0; i < 4; ++i)
                    xq[i] = *reinterpret_cast<const float4*>(&Xs[ty * 4 + i][k0]);
#pragma unroll
                for (int j = 0; j < 4; ++j)
                    wq[j] = *reinterpret_cast<const float4*>(&Ws[k0 + j][tx * 4]);
#pragma unroll
                for (int i = 0; i < 4; ++i) {
                    const float* xa = reinterpret_cast<const float*>(&xq[i]);
#pragma unroll
                    for (int j = 0; j < 4; ++j) {
                        const float* wb = reinterpret_cast<const float*>(&wq[j]);
                        acc[i][0] += xa[j] * wb[0];
                        acc[i][1] += xa[j] * wb[1];
                        acc[i][2] += xa[j] * wb[2];
                        acc[i][3] += xa[j] * wb[3];
                    }
                }
            }
        }
        __syncthreads();
    }
    if (active) {
#pragma unroll
        for (int i = 0; i < 4; ++i) {
            int gr = rowbase + ty * 4 + i;
            if (gr < n) {
                __half2 h0 = __float22half2_rn(make_float2(acc[i][0], acc[i][1]));
                __half2 h1 = __float22half2_rn(make_float2(acc[i][2], acc[i][3]));
                uint2 u;
                u.x = *reinterpret_cast<unsigned int*>(&h0);
                u.y = *reinterpret_cast<unsigned int*>(&h1);
                *reinterpret_cast<uint2*>(H + (size_t)gr * C + tx * 4) = u;
            }
        }
    }
}

// ---- gather over 64-feature fp16 rows: wave per node, 8 lanes x 16 B per
//      edge row, 8 edges in flight; butterfly (xor 8,16,32) combines groups.
template <bool RELU, bool BIAS>
__global__ __launch_bounds__(256) void gather64h_kernel(const __half* __restrict__ Hh,
                                                        const int2* __restrict__ csr,
                                                        const int* __restrict__ counter,
                                                        const float* __restrict__ dinv,
                                                        const float* __restrict__ b,
                                                        __half* __restrict__ Oh, int n) {
    int node = (blockIdx.x * blockDim.x + threadIdx.x) >> 6;
    if (node >= n) return;
    int lane = threadIdx.x & 63;
    int g = lane >> 3;          // 8 edge groups
    int fl = lane & 7;          // 16 B chunk (8 features) within row
    const float4* H4 = reinterpret_cast<const float4*>(Hh);
    int rs = node ? counter[node - 1] : 0;
    int re = counter[node];
    float a[8] = {};
    for (int e = rs + g; e < re; e += 8) {
        int2 c = csr[e];
        float nrm = __int_as_float(c.y);
        float4 raw = H4[(size_t)c.x * 8 + fl];
        const __half2* hp = reinterpret_cast<const __half2*>(&raw);
#pragma unroll
        for (int q = 0; q < 4; ++q) {
            float2 f = __half22float2(hp[q]);
            a[2 * q]     += f.x * nrm;
            a[2 * q + 1] += f.y * nrm;
        }
    }
    if (g == 0) {  // self-loop + bias counted exactly once (pre-butterfly)
        float di = dinv[node];
        float d2 = di * di;
        float4 raw = H4[(size_t)node * 8 + fl];
        const __half2* hp = reinterpret_cast<const __half2*>(&raw);
#pragma unroll
        for (int q = 0; q < 4; ++q) {
            float2 f = __half22float2(hp[q]);
            a[2 * q]     += f.x * d2;
            a[2 * q + 1] += f.y * d2;
        }
        if (BIAS) {
            float4 b0 = reinterpret_cast<const float4*>(b)[fl * 2];
            float4 b1 = reinterpret_cast<const float4*>(b)[fl * 2 + 1];
            a[0] += b0.x; a[1] += b0.y; a[2] += b0.z; a[3] += b0.w;
            a[4] += b1.x; a[5] += b1.y; a[6] += b1.z; a[7] += b1.w;
        }
    }
#pragma unroll
    for (int off = 8; off <= 32; off <<= 1) {
#pragma unroll
        for (int q = 0; q < 8; ++q) a[q] += __shfl_xor(a[q], off);
    }
    if (g == 0) {
        if (RELU) {
#pragma unroll
            for (int q = 0; q < 8; ++q) a[q] = fmaxf(a[q], 0.f);
        }
        float4 o;
        __half2* op = reinterpret_cast<__half2*>(&o);
#pragma unroll
        for (int q = 0; q < 4; ++q)
            op[q] = __float22half2_rn(make_float2(a[2 * q], a[2 * q + 1]));
        *reinterpret_cast<float4*>(Oh + (size_t)node * 64 + fl * 8) = o;
    }
}

// ---- GEMM2 + bias + log_softmax fused: out = log_softmax(X(fp16) @ W2 + b2)
__global__ __launch_bounds__(256) void gemm2_softmax_kernel(const __half* __restrict__ Xh,
                                                            const float* __restrict__ W,
                                                            const float* __restrict__ b,
                                                            float* __restrict__ out, int n) {
    constexpr int BM = 96, K = 64, C = 40, XP = 68, HP = 41;
    __shared__ float Xs[BM * XP];     // reused as Hs[96][41] after compute
    __shared__ float Ws[K * C];
    __shared__ float bs[C];
    __shared__ float rowm[BM], rowls[BM];
    int t = threadIdx.x;
    int tx = t % (C / 4);             // 0..9
    int ty = t / (C / 4);             // 0..25
    bool active = ty < BM / 4;        // ty < 24
    int rowbase = blockIdx.x * BM;

    for (int i = t; i < K * C / 4; i += 256)
        ((float4*)Ws)[i] = ((const float4*)W)[i];
    if (t < C) bs[t] = b[t];
    for (int fi = t; fi < BM * 8; fi += 256) {
        int row = fi >> 3, kq = fi & 7;
        int gr = rowbase + row; if (gr >= n) gr = n - 1;
        float4 raw = reinterpret_cast<const float4*>(Xh + (size_t)gr * K)[kq];
        const __half2* hp = reinterpret_cast<const __half2*>(&raw);
        float2 f0 = __half22float2(hp[0]), f1 = __half22float2(hp[1]);
        float2 f2 = __half22float2(hp[2]), f3 = __half22float2(hp[3]);
        float* dp = &Xs[row * XP + kq * 8];
        *reinterpret_cast<float4*>(dp)     = make_float4(f0.x, f0.y, f1.x, f1.y);
        *reinterpret_cast<float4*>(dp + 4) = make_float4(f2.x, f2.y, f3.x, f3.y);
    }
    __syncthreads();

    float acc[4][4] = {};
    if (active) {
#pragma unroll
        for (int k0 = 0; k0 < K; k0 += 4) {
            float4 xq[4], wq[4];
#pragma unroll
            for (int i = 0; i < 4; ++i)
                xq[i] = *reinterpret_cast<const float4*>(&Xs[(ty * 4 + i) * XP + k0]);
#pragma unroll
            for (int j = 0; j < 4; ++j)
                wq[j] = *reinterpret_cast<const float4*>(&Ws[(k0 + j) * C + tx * 4]);
#pragma unroll
            for (int i = 0; i < 4; ++i) {
                const float* xa = reinterpret_cast<const float*>(&xq[i]);
#pragma unroll
                for (int j = 0; j < 4; ++j) {
                    const float* wb = reinterpret_cast<const float*>(&wq[j]);
                    acc[i][0] += xa[j] * wb[0];
                    acc[i][1] += xa[j] * wb[1];
                    acc[i][2] += xa[j] * wb[2];
                    acc[i][3] += xa[j] * wb[3];
                }
            }
        }
    }
    __syncthreads();                  // everyone done reading Xs
    float* Hs = Xs;                   // reuse as [BM][41]
    if (active) {
#pragma unroll
        for (int i = 0; i < 4; ++i) {
            int r = ty * 4 + i;
#pragma unroll
            for (int j = 0; j < 4; ++j)
                Hs[r * HP + tx * 4 + j] = acc[i][j] + bs[tx * 4 + j];
        }
    }
    __syncthreads();
    if (t < BM) {
        float m = -INFINITY;
        for (int j = 0; j < C; ++j) m = fmaxf(m, Hs[t * HP + j]);
        float s = 0.f;
        for (int j = 0; j < C; ++j) s += __expf(Hs[t * HP + j] - m);
        rowm[t] = m; rowls[t] = __logf(s);
    }
    __syncthreads();
    for (int idx = t; idx < BM * C; idx += 256) {
        int r = idx / C, c = idx - r * C;
        int gr = rowbase + r;
        if (gr < n) out[(size_t)gr * C + c] = Hs[r * HP + c] - rowm[r] - rowls[r];
    }
}

extern "C" void kernel_launch(void* const* d_in, const int* in_sizes, int n_in,
                              void* d_out, int out_size, void* d_ws, size_t ws_size,
                              hipStream_t stream) {
    const float* x  = (const float*)d_in[0];
    const int*   ei = (const int*)d_in[1];
    const float* W1 = (const float*)d_in[2];
    const float* b1 = (const float*)d_in[3];
    const float* W2 = (const float*)d_in[4];
    const float* b2 = (const float*)d_in[5];
    float* out = (float*)d_out;

    const int n = in_sizes[0] / 128;   // 100000
    const int E = in_sizes[1] / 2;     // 800000
    const int* src = ei;
    const int* dst = ei + E;

    auto al = [](size_t x) { return (x + 255) & ~(size_t)255; };
    float* ws = (float*)d_ws;
    size_t o_deg  = 0;                         // n ints -> dinv floats in place
    size_t o_cnt  = al(n);                     // n ints
    size_t o_part = o_cnt + al(n);             // <=256 ints
    size_t o_csr  = o_part + 1024;             // E int2
    size_t o_h1   = o_csr + al((size_t)2 * E); // n*64 halves (h1, later agg2)
    size_t o_out1 = o_h1 + al((size_t)n * 32); // n*64 halves

    int*    degi    = (int*)(ws + o_deg);
    float*  dinv    = (float*)(ws + o_deg);
    int*    counter = (int*)(ws + o_cnt);
    int*    partial = (int*)(ws + o_part);
    int2*   csr     = (int2*)(ws + o_csr);
    __half* h1      = (__half*)(ws + o_h1);
    __half* out1    = (__half*)(ws + o_out1);
    __half* agg2    = (__half*)(ws + o_h1);    // h1 dead after gather #1

    const int NB = (n + 1023) / 1024;

    hipMemsetAsync(degi, 0, (size_t)n * 4, stream);
    deg_int_kernel<<<(E + 255) / 256, 256, 0, stream>>>(dst, degi, E);
    blocksum_kernel<<<NB, 256, 0, stream>>>(degi, partial, n);
    scanp_kernel<<<1, 256, 0, stream>>>(partial, NB);
    offsets_kernel<<<NB, 256, 0, stream>>>(degi, partial, counter, n);
    fill_kernel<<<(E + 255) / 256, 256, 0, stream>>>(src, dst, dinv, counter, csr, E);

    gemm_tiled_h<128, 64, 64><<<(n + 63) / 64, 256, 0, stream>>>(x, W1, h1, n);
    gather64h_kernel<true, true><<<(n + 3) / 4, 256, 0, stream>>>(
        h1, csr, counter, dinv, b1, out1, n);
    gather64h_kernel<false, false><<<(n + 3) / 4, 256, 0, stream>>>(
        out1, csr, counter, dinv, nullptr, agg2, n);
    gemm2_softmax_kernel<<<(n + 95) / 96, 256, 0, stream>>>(agg2, W2, b2, out, n);
}

// Round 5
// 185.920 us; speedup vs baseline: 3.1058x; 1.1874x over previous
//
#include <hip/hip_runtime.h>
#include <hip/hip_bf16.h>
#include <hip/hip_fp16.h>
#include <math.h>

// ---------------------------------------------------------------------------
// GCN 2-layer, CSR-gather formulation, fp16 intermediate storage:
//   rank[e] = atomicAdd(degi[dst[e]],1)      (histogram + rank in one pass)
//   rowstart = exscan(degi); dinv = rsqrt(degi+1)
//   csr[rowstart[t] + rank[e]] = (src, dinv[s]*dinv[t])   (atomic-free fill)
//   h1(fp16) = x @ W1;  out1(fp16) = relu(gather(h1) + self + b1)
//   agg2(fp16) = gather(out1) + self     (linearity: aggregate BEFORE gemm2)
//   out = log_softmax(agg2 @ W2 + b2)    (softmax fused into gemm2 epilogue)
// ---------------------------------------------------------------------------

__global__ void deg_rank_kernel(const int* __restrict__ dst, int* __restrict__ degi,
                                int* __restrict__ rank, int E) {
    int i = blockIdx.x * blockDim.x + threadIdx.x;
    if (i < E) rank[i] = atomicAdd(&degi[dst[i]], 1);
}

// ---- two-level exclusive scan of degi -> rowstart (1024 items / block) ----
__global__ __launch_bounds__(256) void blocksum_kernel(const int* __restrict__ degi,
                                                       int* __restrict__ partial, int n) {
    __shared__ int sm[256];
    int t = threadIdx.x;
    int base = blockIdx.x * 1024 + t * 4;
    int s = 0;
#pragma unroll
    for (int j = 0; j < 4; ++j) { int i = base + j; if (i < n) s += degi[i]; }
    sm[t] = s;
    __syncthreads();
    for (int off = 128; off > 0; off >>= 1) {
        if (t < off) sm[t] += sm[t + off];
        __syncthreads();
    }
    if (t == 0) partial[blockIdx.x] = sm[0];
}

__global__ __launch_bounds__(256) void scanp_kernel(int* __restrict__ partial, int nb) {
    __shared__ int sm[256];
    int t = threadIdx.x;
    int v = (t < nb) ? partial[t] : 0;
    sm[t] = v;
    __syncthreads();
    for (int off = 1; off < 256; off <<= 1) {
        int x = (t >= off) ? sm[t - off] : 0;
        __syncthreads();
        sm[t] += x;
        __syncthreads();
    }
    if (t < nb) partial[t] = sm[t] - v;  // exclusive
}

// rowstart = exscan(degi); also degi <- rsqrt(degi+1) in place (dinv)
__global__ __launch_bounds__(256) void offsets_kernel(int* __restrict__ degi,
                                                      const int* __restrict__ partial,
                                                      int* __restrict__ rowstart, int n) {
    __shared__ int sm[256];
    int t = threadIdx.x;
    int base = blockIdx.x * 1024 + t * 4;
    int v[4]; int s = 0;
#pragma unroll
    for (int j = 0; j < 4; ++j) { v[j] = (base + j < n) ? degi[base + j] : 0; s += v[j]; }
    sm[t] = s;
    __syncthreads();
    for (int off = 1; off < 256; off <<= 1) {
        int x = (t >= off) ? sm[t - off] : 0;
        __syncthreads();
        sm[t] += x;
        __syncthreads();
    }
    int run = partial[blockIdx.x] + (sm[t] - s);
#pragma unroll
    for (int j = 0; j < 4; ++j) {
        if (base + j < n) {
            rowstart[base + j] = run; run += v[j];
            ((float*)degi)[base + j] = rsqrtf((float)v[j] + 1.0f);  // +1 self-loop
        }
    }
}

// atomic-free fill: pos = rowstart[t] + rank[e]
__global__ void fill_kernel(const int* __restrict__ src, const int* __restrict__ dst,
                            const int* __restrict__ rank, const float* __restrict__ dinv,
                            const int* __restrict__ rowstart, int2* __restrict__ csr, int E) {
    int e = blockIdx.x * blockDim.x + threadIdx.x;
    if (e >= E) return;
    int s = src[e], t = dst[e];
    float nrm = dinv[s] * dinv[t];
    int pos = rowstart[t] + rank[e];
    csr[pos] = make_int2(s, __float_as_int(nrm));
}

// ---- GEMM1: H[n,64](fp16) = X[n,128] @ W[128,64], 4x4 regs/thread ----
template <int K, int C, int BM>
__global__ __launch_bounds__(256) void gemm_tiled_h(const float* __restrict__ X,
                                                    const float* __restrict__ W,
                                                    __half* __restrict__ H, int n) {
    constexpr int BK = 32;
    constexpr int XP = 36;
    constexpr int ROWG = BM / 4;
    constexpr int COLG = C / 4;
    __shared__ float Xs[BM][XP];
    __shared__ float Ws[BK][C];
    int t = threadIdx.x;
    int tx = t % COLG;
    int ty = t / COLG;
    bool active = ty < ROWG;
    int rowbase = blockIdx.x * BM;
    float acc[4][4] = {};

    for (int kc = 0; kc < K; kc += BK) {
        for (int fi = t; fi < BM * 8; fi += 256) {
            int row = fi >> 3, kq = fi & 7;
            int gr = rowbase + row; if (gr >= n) gr = n - 1;
            float4 v = *reinterpret_cast<const float4*>(X + (size_t)gr * K + kc + kq * 4);
            *reinterpret_cast<float4*>(&Xs[row][kq * 4]) = v;
        }
        for (int fi = t; fi < BK * C / 4; fi += 256) {
            reinterpret_cast<float4*>(&Ws[0][0])[fi] =
                reinterpret_cast<const float4*>(W + (size_t)kc * C)[fi];
        }
        __syncthreads();
        if (active) {
#pragma unroll
            for (int k0 = 0; k0 < BK; k0 += 4) {
                float4 xq[4], wq[4];
#pragma unroll
                for (int i = 0; i < 4; ++i)
                    xq[i] = *reinterpret_cast<const float4*>(&Xs[ty * 4 + i][k0]);
#pragma unroll
                for (int j = 0; j < 4; ++j)
                    wq[j] = *reinterpret_cast<const float4*>(&Ws[k0 + j][tx * 4]);
#pragma unroll
                for (int i = 0; i < 4; ++i) {
                    const float* xa = reinterpret_cast<const float*>(&xq[i]);
#pragma unroll
                    for (int j = 0; j < 4; ++j) {
                        const float* wb = reinterpret_cast<const float*>(&wq[j]);
                        acc[i][0] += xa[j] * wb[0];
                        acc[i][1] += xa[j] * wb[1];
                        acc[i][2] += xa[j] * wb[2];
                        acc[i][3] += xa[j] * wb[3];
                    }
                }
            }
        }
        __syncthreads();
    }
    if (active) {
#pragma unroll
        for (int i = 0; i < 4; ++i) {
            int gr = rowbase + ty * 4 + i;
            if (gr < n) {
                __half2 h0 = __float22half2_rn(make_float2(acc[i][0], acc[i][1]));
                __half2 h1 = __float22half2_rn(make_float2(acc[i][2], acc[i][3]));
                uint2 u;
                u.x = *reinterpret_cast<unsigned int*>(&h0);
                u.y = *reinterpret_cast<unsigned int*>(&h1);
                *reinterpret_cast<uint2*>(H + (size_t)gr * C + tx * 4) = u;
            }
        }
    }
}

// ---- gather over 64-feature fp16 rows: wave per node, 8 lanes x 16 B per
//      edge row, 2x unrolled => 16 edges / wave in flight; butterfly xor
//      {8,16,32} combines the 8 groups.
template <bool RELU, bool BIAS>
__global__ __launch_bounds__(256) void gather64h_kernel(const __half* __restrict__ Hh,
                                                        const int2* __restrict__ csr,
                                                        const int* __restrict__ rowstart,
                                                        const float* __restrict__ dinv,
                                                        const float* __restrict__ b,
                                                        __half* __restrict__ Oh, int n, int E) {
    int node = (blockIdx.x * blockDim.x + threadIdx.x) >> 6;
    if (node >= n) return;
    int lane = threadIdx.x & 63;
    int g = lane >> 3;          // 8 edge groups
    int fl = lane & 7;          // 16 B chunk (8 features) within row
    const float4* H4 = reinterpret_cast<const float4*>(Hh);
    int rs = rowstart[node];
    int re = (node + 1 < n) ? rowstart[node + 1] : E;
    float a[8] = {};
    for (int e = rs + g; e < re; e += 16) {
        int2 c0 = csr[e];
        bool has2 = (e + 8) < re;
        int e1 = has2 ? e + 8 : e;
        int2 c1 = csr[e1];
        float nrm0 = __int_as_float(c0.y);
        float nrm1 = has2 ? __int_as_float(c1.y) : 0.0f;
        float4 raw0 = H4[(size_t)c0.x * 8 + fl];
        float4 raw1 = H4[(size_t)c1.x * 8 + fl];
        const __half2* h0 = reinterpret_cast<const __half2*>(&raw0);
        const __half2* h1 = reinterpret_cast<const __half2*>(&raw1);
#pragma unroll
        for (int q = 0; q < 4; ++q) {
            float2 f0 = __half22float2(h0[q]);
            float2 f1 = __half22float2(h1[q]);
            a[2 * q]     += f0.x * nrm0 + f1.x * nrm1;
            a[2 * q + 1] += f0.y * nrm0 + f1.y * nrm1;
        }
    }
    if (g == 0) {  // self-loop + bias counted exactly once (pre-butterfly)
        float di = dinv[node];
        float d2 = di * di;
        float4 raw = H4[(size_t)node * 8 + fl];
        const __half2* hp = reinterpret_cast<const __half2*>(&raw);
#pragma unroll
        for (int q = 0; q < 4; ++q) {
            float2 f = __half22float2(hp[q]);
            a[2 * q]     += f.x * d2;
            a[2 * q + 1] += f.y * d2;
        }
        if (BIAS) {
            float4 b0 = reinterpret_cast<const float4*>(b)[fl * 2];
            float4 b1 = reinterpret_cast<const float4*>(b)[fl * 2 + 1];
            a[0] += b0.x; a[1] += b0.y; a[2] += b0.z; a[3] += b0.w;
            a[4] += b1.x; a[5] += b1.y; a[6] += b1.z; a[7] += b1.w;
        }
    }
#pragma unroll
    for (int off = 8; off <= 32; off <<= 1) {
#pragma unroll
        for (int q = 0; q < 8; ++q) a[q] += __shfl_xor(a[q], off);
    }
    if (g == 0) {
        if (RELU) {
#pragma unroll
            for (int q = 0; q < 8; ++q) a[q] = fmaxf(a[q], 0.f);
        }
        float4 o;
        __half2* op = reinterpret_cast<__half2*>(&o);
#pragma unroll
        for (int q = 0; q < 4; ++q)
            op[q] = __float22half2_rn(make_float2(a[2 * q], a[2 * q + 1]));
        *reinterpret_cast<float4*>(Oh + (size_t)node * 64 + fl * 8) = o;
    }
}

// ---- GEMM2 + bias + log_softmax fused: out = log_softmax(X(fp16) @ W2 + b2)
__global__ __launch_bounds__(256) void gemm2_softmax_kernel(const __half* __restrict__ Xh,
                                                            const float* __restrict__ W,
                                                            const float* __restrict__ b,
                                                            float* __restrict__ out, int n) {
    constexpr int BM = 96, K = 64, C = 40, XP = 68, HP = 41;
    __shared__ float Xs[BM * XP];     // reused as Hs[96][41] after compute
    __shared__ float Ws[K * C];
    __shared__ float bs[C];
    __shared__ float rowm[BM], rowls[BM];
    int t = threadIdx.x;
    int tx = t % (C / 4);             // 0..9
    int ty = t / (C / 4);             // 0..25
    bool active = ty < BM / 4;        // ty < 24
    int rowbase = blockIdx.x * BM;

    for (int i = t; i < K * C / 4; i += 256)
        ((float4*)Ws)[i] = ((const float4*)W)[i];
    if (t < C) bs[t] = b[t];
    for (int fi = t; fi < BM * 8; fi += 256) {
        int row = fi >> 3, kq = fi & 7;
        int gr = rowbase + row; if (gr >= n) gr = n - 1;
        float4 raw = reinterpret_cast<const float4*>(Xh + (size_t)gr * K)[kq];
        const __half2* hp = reinterpret_cast<const __half2*>(&raw);
        float2 f0 = __half22float2(hp[0]), f1 = __half22float2(hp[1]);
        float2 f2 = __half22float2(hp[2]), f3 = __half22float2(hp[3]);
        float* dp = &Xs[row * XP + kq * 8];
        *reinterpret_cast<float4*>(dp)     = make_float4(f0.x, f0.y, f1.x, f1.y);
        *reinterpret_cast<float4*>(dp + 4) = make_float4(f2.x, f2.y, f3.x, f3.y);
    }
    __syncthreads();

    float acc[4][4] = {};
    if (active) {
#pragma unroll
        for (int k0 = 0; k0 < K; k0 += 4) {
            float4 xq[4], wq[4];
#pragma unroll
            for (int i = 0; i < 4; ++i)
                xq[i] = *reinterpret_cast<const float4*>(&Xs[(ty * 4 + i) * XP + k0]);
#pragma unroll
            for (int j = 0; j < 4; ++j)
                wq[j] = *reinterpret_cast<const float4*>(&Ws[(k0 + j) * C + tx * 4]);
#pragma unroll
            for (int i = 0; i < 4; ++i) {
                const float* xa = reinterpret_cast<const float*>(&xq[i]);
#pragma unroll
                for (int j = 0; j < 4; ++j) {
                    const float* wb = reinterpret_cast<const float*>(&wq[j]);
                    acc[i][0] += xa[j] * wb[0];
                    acc[i][1] += xa[j] * wb[1];
                    acc[i][2] += xa[j] * wb[2];
                    acc[i][3] += xa[j] * wb[3];
                }
            }
        }
    }
    __syncthreads();                  // everyone done reading Xs
    float* Hs = Xs;                   // reuse as [BM][41]
    if (active) {
#pragma unroll
        for (int i = 0; i < 4; ++i) {
            int r = ty * 4 + i;
#pragma unroll
            for (int j = 0; j < 4; ++j)
                Hs[r * HP + tx * 4 + j] = acc[i][j] + bs[tx * 4 + j];
        }
    }
    __syncthreads();
    if (t < BM) {
        float m = -INFINITY;
        for (int j = 0; j < C; ++j) m = fmaxf(m, Hs[t * HP + j]);
        float s = 0.f;
        for (int j = 0; j < C; ++j) s += __expf(Hs[t * HP + j] - m);
        rowm[t] = m; rowls[t] = __logf(s);
    }
    __syncthreads();
    for (int idx = t; idx < BM * C; idx += 256) {
        int r = idx / C, c = idx - r * C;
        int gr = rowbase + r;
        if (gr < n) out[(size_t)gr * C + c] = Hs[r * HP + c] - rowm[r] - rowls[r];
    }
}

extern "C" void kernel_launch(void* const* d_in, const int* in_sizes, int n_in,
                              void* d_out, int out_size, void* d_ws, size_t ws_size,
                              hipStream_t stream) {
    const float* x  = (const float*)d_in[0];
    const int*   ei = (const int*)d_in[1];
    const float* W1 = (const float*)d_in[2];
    const float* b1 = (const float*)d_in[3];
    const float* W2 = (const float*)d_in[4];
    const float* b2 = (const float*)d_in[5];
    float* out = (float*)d_out;

    const int n = in_sizes[0] / 128;   // 100000
    const int E = in_sizes[1] / 2;     // 800000
    const int* src = ei;
    const int* dst = ei + E;

    auto al = [](size_t x) { return (x + 255) & ~(size_t)255; };
    float* ws = (float*)d_ws;
    size_t o_deg  = 0;                          // n ints -> dinv floats in place
    size_t o_cnt  = al(n);                      // n ints (rowstart)
    size_t o_part = o_cnt + al(n);              // <=256 ints
    size_t o_rank = o_part + 1024;              // E ints
    size_t o_csr  = o_rank + al(E);             // E int2
    size_t o_h1   = o_csr + al((size_t)2 * E);  // n*64 halves (h1, later agg2)
    size_t o_out1 = o_h1 + al((size_t)n * 32);  // n*64 halves

    int*    degi     = (int*)(ws + o_deg);
    float*  dinv     = (float*)(ws + o_deg);
    int*    rowstart = (int*)(ws + o_cnt);
    int*    partial  = (int*)(ws + o_part);
    int*    rank     = (int*)(ws + o_rank);
    int2*   csr      = (int2*)(ws + o_csr);
    __half* h1       = (__half*)(ws + o_h1);
    __half* out1     = (__half*)(ws + o_out1);
    __half* agg2     = (__half*)(ws + o_h1);    // h1 dead after gather #1

    const int NB = (n + 1023) / 1024;

    hipMemsetAsync(degi, 0, (size_t)n * 4, stream);
    deg_rank_kernel<<<(E + 255) / 256, 256, 0, stream>>>(dst, degi, rank, E);
    blocksum_kernel<<<NB, 256, 0, stream>>>(degi, partial, n);
    scanp_kernel<<<1, 256, 0, stream>>>(partial, NB);
    offsets_kernel<<<NB, 256, 0, stream>>>(degi, partial, rowstart, n);
    fill_kernel<<<(E + 255) / 256, 256, 0, stream>>>(src, dst, rank, dinv, rowstart, csr, E);

    gemm_tiled_h<128, 64, 64><<<(n + 63) / 64, 256, 0, stream>>>(x, W1, h1, n);
    gather64h_kernel<true, true><<<(n + 3) / 4, 256, 0, stream>>>(
        h1, csr, rowstart, dinv, b1, out1, n, E);
    gather64h_kernel<false, false><<<(n + 3) / 4, 256, 0, stream>>>(
        out1, csr, rowstart, dinv, nullptr, agg2, n, E);
    gemm2_softmax_kernel<<<(n + 95) / 96, 256, 0, stream>>>(agg2, W2, b2, out, n);
}